// Round 4
// baseline (224.732 us; speedup 1.0000x reference)
//
#include <hip/hip_runtime.h>
#include <math.h>

#define HIDN 512
#define PROJ 1024
#define ATTN 128
#define BATCH 4
#define SEQ 2048
#define N1 (2*PROJ+ATTN)      // 2176
#define ROWS (BATCH*SEQ)      // 8192
#define QR 16                 // q-rows per attnsm block

typedef __attribute__((ext_vector_type(4))) float f32x4;
typedef __attribute__((ext_vector_type(8))) short bf16x8;

// bf16 <-> f32 via bit ops (round-to-nearest-even), no header dependency
__device__ __forceinline__ short f2bf(float x){
    unsigned u = __builtin_bit_cast(unsigned, x);
    unsigned rounding = 0x7fffu + ((u >> 16) & 1u);
    u += rounding;
    return (short)(u >> 16);
}
__device__ __forceinline__ float bf2f(short s){
    unsigned u = ((unsigned)(unsigned short)s) << 16;
    return __builtin_bit_cast(float, u);
}

__device__ __forceinline__ void gload16(const void* g, void* l){
    __builtin_amdgcn_global_load_lds((const __attribute__((address_space(1))) void*)g,
                                     (__attribute__((address_space(3))) void*)l,
                                     16, 0, 0);
}

// ---------------- m97-style bt-GEMM tile: C[128x128] = A[M][K] @ BT[N][K]^T
// 256 threads (4 waves, 2x2), 16x16x32 bf16 MFMA, single-buffered LDS.
template<class Epi>
__device__ __forceinline__ void gemm_bt_tile(const short* __restrict__ A, int lda,
                                             const short* __restrict__ BT, int ldb,
                                             int m0, int n0, int K, Epi epi)
{
    __shared__ __align__(16) short lA[128*64];
    __shared__ __align__(16) short lB[128*64];
    const int t = threadIdx.x;
    const int lane = t & 63;
    const int w = t >> 6;
    const int wr = (w >> 1) * 64, wc = (w & 1) * 64;
    const int half = lane >> 4, l16 = lane & 15;

    f32x4 acc[4][4];
    #pragma unroll
    for (int i=0;i<4;i++)
        #pragma unroll
        for (int j=0;j<4;j++)
            acc[i][j] = (f32x4){0.f,0.f,0.f,0.f};

    for (int k0 = 0; k0 < K; k0 += 64) {
        #pragma unroll
        for (int i = 0; i < 4; i++) {
            int li = i*256 + t;
            int r = li >> 3, s = li & 7;
            gload16(A + (size_t)(m0+r)*lda + k0 + s*8, lA + li*8);
        }
        #pragma unroll
        for (int i = 0; i < 4; i++) {
            int li = i*256 + t;
            int r = li >> 3, s = li & 7;
            gload16(BT + (size_t)(n0+r)*ldb + k0 + s*8, lB + li*8);
        }
        __syncthreads();
        #pragma unroll
        for (int kk = 0; kk < 64; kk += 32) {
            bf16x8 af[4], bfr[4];
            #pragma unroll
            for (int i=0;i<4;i++)
                af[i] = *(const bf16x8*)(lA + (wr + i*16 + l16)*64 + kk + half*8);
            #pragma unroll
            for (int j=0;j<4;j++)
                bfr[j] = *(const bf16x8*)(lB + (wc + j*16 + l16)*64 + kk + half*8);
            #pragma unroll
            for (int i=0;i<4;i++)
                #pragma unroll
                for (int j=0;j<4;j++)
                    acc[i][j] = __builtin_amdgcn_mfma_f32_16x16x32_bf16(af[i], bfr[j], acc[i][j], 0, 0, 0);
        }
        __syncthreads();
    }
    // C/D layout: col = lane&15, row = (lane>>4)*4 + q   [m89/m91 verified]
    #pragma unroll
    for (int i=0;i<4;i++)
        #pragma unroll
        for (int j=0;j<4;j++)
            #pragma unroll
            for (int q=0;q<4;q++)
                epi(m0 + wr + i*16 + half*4 + q, n0 + wc + j*16 + l16, acc[i][j][q]);
}

// ---------------- helpers ----------------
__global__ void k_cast_node(const float* __restrict__ in, short* __restrict__ out){
    int idx = blockIdx.x*256 + threadIdx.x;     // 4 elems each
    const float4 v = ((const float4*)in)[idx];
    short4 o; o.x = f2bf(v.x); o.y = f2bf(v.y); o.z = f2bf(v.z); o.w = f2bf(v.w);
    ((short4*)out)[idx] = o;
}

// out[c][r] = bf16(in[r][c]);  in: f32 [R][C]
__global__ void k_transpose_cast(const float* __restrict__ in, short* __restrict__ out,
                                 int R, int C){
    __shared__ short tile[64][65];
    int r0 = blockIdx.y*64, c0 = blockIdx.x*64;
    int t = threadIdx.x;
    #pragma unroll
    for (int i=0;i<16;i++){
        int lin = i*256 + t; int r = lin>>6, c = lin&63;
        tile[r][c] = f2bf(in[(size_t)(r0+r)*C + c0+c]);
    }
    __syncthreads();
    #pragma unroll
    for (int i=0;i<16;i++){
        int lin = i*256 + t; int c = lin>>6, r = lin&63;
        out[(size_t)(c0+c)*R + r0+r] = tile[r][c];
    }
}

// per-batch transpose: VT[z][c][r] = values[z*SEQ + r][c]   (bf16)
__global__ void k_transpose_v(const short* __restrict__ values, short* __restrict__ VT){
    __shared__ short tile[64][65];
    int z = blockIdx.z;
    int c0 = blockIdx.x*64, r0 = blockIdx.y*64;
    int t = threadIdx.x;
    #pragma unroll
    for (int i=0;i<16;i++){
        int lin = i*256 + t; int r = lin>>6, c = lin&63;
        tile[r][c] = values[(size_t)(z*SEQ + r0+r)*PROJ + c0+c];
    }
    __syncthreads();
    #pragma unroll
    for (int i=0;i<16;i++){
        int lin = i*256 + t; int c = lin>>6, r = lin&63;
        VT[((size_t)z*PROJ + c0+c)*SEQ + r0+r] = tile[r][c];
    }
}

// ---------------- GEMM1: silu(node@w1+b1) -> gates/values/base (bf16)
__global__ __launch_bounds__(256) void k_mm1(const short* __restrict__ nodeb,
        const short* __restrict__ w1T, const float* __restrict__ b1,
        short* __restrict__ gates, short* __restrict__ values, short* __restrict__ baseb){
    int n0 = blockIdx.x*128, m0 = blockIdx.y*128;
    gemm_bt_tile(nodeb, HIDN, w1T, HIDN, m0, n0, HIDN,
        [=](int row, int col, float v){
            v += b1[col];
            v = v / (1.f + __expf(-v));
            short bv = f2bf(v);
            if (col < PROJ)        gates [(size_t)row*PROJ + col]        = bv;
            else if (col < 2*PROJ) values[(size_t)row*PROJ + col-PROJ]   = bv;
            else                   baseb [(size_t)row*ATTN + col-2*PROJ] = bv;
        });
}

// ---------------- RoPE: affine + rotate, q pre-scaled (bf16 in/out)
__global__ void k_rope2(const short* __restrict__ baseb, const float* __restrict__ msw,
                        const float* __restrict__ msb, const float* __restrict__ scaling,
                        short* __restrict__ qb, short* __restrict__ kb){
    int idx = blockIdx.x*256 + threadIdx.x;     // ROWS*64
    int d = idx & 63;
    int row = idx >> 6;
    int l = row & (SEQ-1);
    float inv = exp2f(-(float)d * (13.287712379549449f/64.f));   // 10000^(-d/64)
    float ang = (float)l * inv;
    float s = sinf(ang), c = cosf(ang);
    const short* bp = baseb + (size_t)row*ATTN;
    float b_lo = bf2f(bp[d]), b_hi = bf2f(bp[d+64]);
    float x1q = b_lo*msw[d]        + msb[d];
    float x2q = b_hi*msw[d+64]     + msb[d+64];
    float x1k = b_lo*msw[128+d]    + msb[128+d];
    float x2k = b_hi*msw[128+d+64] + msb[128+d+64];
    float sc = scaling[0];
    qb[(size_t)row*ATTN + d]    = f2bf((x1q*c - x2q*s)*sc);
    qb[(size_t)row*ATTN + d+64] = f2bf((x2q*c + x1q*s)*sc);
    kb[(size_t)row*ATTN + d]    = f2bf(x1k*c - x2k*s);
    kb[(size_t)row*ATTN + d+64] = f2bf(x2k*c + x1k*s);
}

// ---------------- fused QK^T + bias + softmax -> compact bf16 P
// One block = 16 q-rows. Traversal 1: online (m,l) per row, all in-register.
// Traversal 2: recompute S tiles (QK is cheap), emit P = exp(s-m)/l via LDS bounce.
__global__ __launch_bounds__(256) void k_attnsm(
        const short* __restrict__ qg, const short* __restrict__ kg,
        const float* __restrict__ bias, short* __restrict__ P)
{
    __shared__ float sm_m[4][QR];
    __shared__ float sm_l[4][QR];
    __shared__ __align__(16) short ptile[QR*128];   // 4KB

    const int z = blockIdx.y;
    const int r0 = blockIdx.x * QR;
    const int t = threadIdx.x;
    const int w = t >> 6;                 // wave -> 32-col slice of each 128 tile
    const int lane = t & 63;
    const int l16 = lane & 15, half = lane >> 4;

    const short* Q  = qg + ((size_t)z*SEQ + r0)*ATTN;
    const short* K  = kg + (size_t)z*SEQ*ATTN;
    const float* Bb = bias + ((size_t)z*SEQ + r0)*SEQ;
    short* Pp = P + ((size_t)z*SEQ + r0)*SEQ;

    // Q A-frags (held in registers for whole kernel): lane row=l16, k=kc*32+half*8
    bf16x8 qf[4];
    #pragma unroll
    for (int kc=0;kc<4;kc++)
        qf[kc] = *(const bf16x8*)(Q + (size_t)l16*ATTN + kc*32 + half*8);

    float m_[4], l_[4];
    #pragma unroll
    for (int q=0;q<4;q++){ m_[q] = -1e30f; l_[q] = 0.f; }

    // ---- traversal 1: stats only
    for (int j=0;j<16;j++){
        f32x4 acc[2];
        acc[0] = (f32x4){0,0,0,0}; acc[1] = (f32x4){0,0,0,0};
        #pragma unroll
        for (int cf=0;cf<2;cf++){
            const short* Kc = K + (size_t)(j*128 + w*32 + cf*16 + l16)*ATTN;
            #pragma unroll
            for (int kc=0;kc<4;kc++){
                bf16x8 kf = *(const bf16x8*)(Kc + kc*32 + half*8);
                acc[cf] = __builtin_amdgcn_mfma_f32_16x16x32_bf16(qf[kc], kf, acc[cf], 0,0,0);
            }
        }
        const int cbase = j*128 + w*32 + l16;
        #pragma unroll
        for (int cf=0;cf<2;cf++)
            #pragma unroll
            for (int q=0;q<4;q++)
                acc[cf][q] += Bb[(size_t)(half*4+q)*SEQ + cbase + cf*16];
        #pragma unroll
        for (int q=0;q<4;q++){
            float tmax = fmaxf(acc[0][q], acc[1][q]);
            #pragma unroll
            for (int off=1; off<16; off<<=1) tmax = fmaxf(tmax, __shfl_xor(tmax, off, 64));
            float mn = fmaxf(m_[q], tmax);
            float ts = __expf(acc[0][q]-mn) + __expf(acc[1][q]-mn);
            #pragma unroll
            for (int off=1; off<16; off<<=1) ts += __shfl_xor(ts, off, 64);
            l_[q] = l_[q]*__expf(m_[q]-mn) + ts;
            m_[q] = mn;
        }
    }
    // ---- combine across 4 waves
    if (l16 == 0){
        #pragma unroll
        for (int q=0;q<4;q++){ sm_m[w][half*4+q] = m_[q]; sm_l[w][half*4+q] = l_[q]; }
    }
    __syncthreads();
    float fm[4], fil[4];
    #pragma unroll
    for (int q=0;q<4;q++){
        int r = half*4+q;
        float mm = fmaxf(fmaxf(sm_m[0][r],sm_m[1][r]), fmaxf(sm_m[2][r],sm_m[3][r]));
        float ll = sm_l[0][r]*__expf(sm_m[0][r]-mm) + sm_l[1][r]*__expf(sm_m[1][r]-mm)
                 + sm_l[2][r]*__expf(sm_m[2][r]-mm) + sm_l[3][r]*__expf(sm_m[3][r]-mm);
        fm[q] = mm; fil[q] = 1.f/ll;
    }
    __syncthreads();

    // ---- traversal 2: recompute S, emit P
    for (int j=0;j<16;j++){
        f32x4 acc[2];
        acc[0] = (f32x4){0,0,0,0}; acc[1] = (f32x4){0,0,0,0};
        #pragma unroll
        for (int cf=0;cf<2;cf++){
            const short* Kc = K + (size_t)(j*128 + w*32 + cf*16 + l16)*ATTN;
            #pragma unroll
            for (int kc=0;kc<4;kc++){
                bf16x8 kf = *(const bf16x8*)(Kc + kc*32 + half*8);
                acc[cf] = __builtin_amdgcn_mfma_f32_16x16x32_bf16(qf[kc], kf, acc[cf], 0,0,0);
            }
        }
        const int cbase = j*128 + w*32 + l16;
        #pragma unroll
        for (int cf=0;cf<2;cf++)
            #pragma unroll
            for (int q=0;q<4;q++){
                float s = acc[cf][q] + Bb[(size_t)(half*4+q)*SEQ + cbase + cf*16];
                float p = __expf(s - fm[q]) * fil[q];
                ptile[(half*4+q)*128 + w*32 + cf*16 + l16] = f2bf(p);
            }
        __syncthreads();
        // stream 16x128 bf16 tile out, short8 per thread
        {
            int idx = t*8;
            int pr = idx >> 7, pc = idx & 127;
            *(bf16x8*)(Pp + (size_t)pr*SEQ + j*128 + pc) = *(const bf16x8*)(ptile + idx);
        }
        __syncthreads();
    }
}

// ---------------- PV: a2 = (P @ V) * gates  (bf16 out)
__global__ __launch_bounds__(256) void k_pv2(const short* __restrict__ P,
        const short* __restrict__ VT, const short* __restrict__ gates,
        short* __restrict__ a2){
    int z = blockIdx.z;
    const short* A = P  + (size_t)z*SEQ*SEQ;       // compact bf16, lda = SEQ
    const short* B = VT + (size_t)z*PROJ*SEQ;      // ldb = SEQ
    int n0 = blockIdx.x*128, m0 = blockIdx.y*128;
    gemm_bt_tile(A, SEQ, B, SEQ, m0, n0, SEQ,
        [=](int r, int c, float v){
            size_t gi = ((size_t)z*SEQ + r)*PROJ + c;
            a2[gi] = f2bf(v * bf2f(gates[gi]));
        });
}

// ---------------- GEMM2: out = a2 @ w2 + b2  (f32 out)
__global__ __launch_bounds__(256) void k_mm2(const short* __restrict__ a2,
        const short* __restrict__ w2T, const float* __restrict__ b2,
        float* __restrict__ out){
    int n0 = blockIdx.x*128, m0 = blockIdx.y*128;
    gemm_bt_tile(a2, PROJ, w2T, PROJ, m0, n0, PROJ,
        [=](int r, int c, float v){
            out[(size_t)r*HIDN + c] = v + b2[c];
        });
}

extern "C" void kernel_launch(void* const* d_in, const int* in_sizes, int n_in,
                              void* d_out, int out_size, void* d_ws, size_t ws_size,
                              hipStream_t stream) {
    const float* node    = (const float*)d_in[0];
    const float* bias    = (const float*)d_in[1];
    const float* scaling = (const float*)d_in[2];
    const float* w1      = (const float*)d_in[3];
    const float* b1      = (const float*)d_in[4];
    const float* msw     = (const float*)d_in[5];
    const float* msb     = (const float*)d_in[6];
    const float* w2      = (const float*)d_in[7];
    const float* b2      = (const float*)d_in[8];
    float* out = (float*)d_out;

    char* p = (char*)d_ws;
    auto alloc = [&](size_t bytes){ char* r = p; p += (bytes + 255) & ~(size_t)255; return r; };
    short* nodeb  = (short*)alloc((size_t)ROWS*HIDN*2);        // 8.4 MB
    short* w1T    = (short*)alloc((size_t)N1*HIDN*2);          // 2.2 MB
    short* w2T    = (short*)alloc((size_t)HIDN*PROJ*2);        // 1.0 MB
    short* gates  = (short*)alloc((size_t)ROWS*PROJ*2);        // 16.8 MB
    short* values = (short*)alloc((size_t)ROWS*PROJ*2);        // 16.8 MB
    short* VT     = (short*)alloc((size_t)BATCH*PROJ*SEQ*2);   // 16.8 MB
    short* baseb  = (short*)alloc((size_t)ROWS*ATTN*2);        // 2.1 MB
    short* qb     = (short*)alloc((size_t)ROWS*ATTN*2);        // 2.1 MB
    short* kb     = (short*)alloc((size_t)ROWS*ATTN*2);        // 2.1 MB
    short* Pbuf   = (short*)alloc((size_t)BATCH*SEQ*SEQ*2);    // 33.6 MB
    short* a2     = (short*)alloc((size_t)ROWS*PROJ*2);        // 16.8 MB

    // prep casts / transposes
    k_cast_node<<<ROWS*HIDN/1024, 256, 0, stream>>>(node, nodeb);
    k_transpose_cast<<<dim3(N1/64, HIDN/64), 256, 0, stream>>>(w1, w1T, HIDN, N1);
    k_transpose_cast<<<dim3(HIDN/64, PROJ/64), 256, 0, stream>>>(w2, w2T, PROJ, HIDN);
    // 1) gva = silu(node@w1+b1)
    k_mm1<<<dim3(N1/128, ROWS/128), 256, 0, stream>>>(nodeb, w1T, b1, gates, values, baseb);
    // transpose values for PV's B^T layout
    k_transpose_v<<<dim3(PROJ/64, SEQ/64, BATCH), 256, 0, stream>>>(values, VT);
    // 2) rope
    k_rope2<<<ROWS*64/256, 256, 0, stream>>>(baseb, msw, msb, scaling, qb, kb);
    // 3) fused qk^T + bias + softmax -> P (bf16)
    k_attnsm<<<dim3(SEQ/QR, BATCH), 256, 0, stream>>>(qb, kb, bias, Pbuf);
    // 3c) a2 = (P@V)*gates
    k_pv2<<<dim3(PROJ/128, SEQ/128, BATCH), 256, 0, stream>>>(Pbuf, VT, gates, a2);
    // 4) out = a2@w2 + b2
    k_mm2<<<dim3(HIDN/128, ROWS/128), 256, 0, stream>>>(a2, w2T, b2, out);
}